// Round 11
// baseline (503.039 us; speedup 1.0000x reference)
//
#include <hip/hip_runtime.h>
#include <hip/hip_fp16.h>
#include <hip/hip_cooperative_groups.h>
#include <math.h>

namespace cg = cooperative_groups;

#define N_NODES 100000
#define D_FEAT  128
#define E_EDGES 1600000
#define E2      (E_EDGES + N_NODES)   /* 1,700,000 with self-loops */
#define NEG_SLOPE 0.2f
#define LN_EPS    1e-5f

#define NB   391                      /* buckets of 256 nodes: d >> 8 */
#define TS   8192                     /* edges per tile */
#define NTIL ((E2 + TS - 1) / TS)     /* 208 */

typedef __attribute__((ext_vector_type(4))) float floatx4;
typedef _Float16 h2 __attribute__((ext_vector_type(2)));   // packed half pair
typedef _Float16 h8 __attribute__((ext_vector_type(8)));   // fp16 MFMA fragment

static __device__ __forceinline__ float fdot2f(h2 a, h2 b, float c) {
#if __has_builtin(__builtin_amdgcn_fdot2)
    return __builtin_amdgcn_fdot2(a, b, c, false);
#else
    return (float)a[0] * (float)b[0] + (float)a[1] * (float)b[1] + c;
#endif
}

static __device__ __forceinline__ h2 shfl_xor_h2(h2 v, int off) {
    int i = __builtin_bit_cast(int, v);
    i = __shfl_xor(i, off);
    return __builtin_bit_cast(h2, i);
}

// ---------------------------------------------------------------------------
// CSR build v15: the ENTIRE prep + 5-kernel radix chain fused into ONE
// cooperative kernel (256 blocks x 1024 = 1 block/CU, co-resident) with
// grid.sync() between phases.  v14 accounting: chain wall ~176us vs ~40us of
// real work -> launch ramp/drain/serialization dominated.  Same algorithm,
// same buffers, same numerics as v12/v14.
// ---------------------------------------------------------------------------
__global__ __launch_bounds__(1024) void csr_fused(
        const int* __restrict__ edge_src, const int* __restrict__ edge_dst,
        const float* __restrict__ Wl, const float* __restrict__ Wr,
        const float* __restrict__ att,
        _Float16* __restrict__ Wt, _Float16* __restrict__ atth,
        int* __restrict__ tcnt, int* __restrict__ toff,
        int* __restrict__ bcnt, int* __restrict__ bstart,
        unsigned short* __restrict__ rankbuf, unsigned* __restrict__ pairbuf,
        int* __restrict__ rowstart, int* __restrict__ csr_src) {
    cg::grid_group grid = cg::this_grid();
    __shared__ int sh[1024];
    __shared__ int sh2[256];
    const int t = threadIdx.x;
    const int b = blockIdx.x;

    // ---- phase 0: weight prep (independent; consumed later by gemm) ----
    {
        int gid = b * 1024 + t;
        if (gid < 65536) {                   // 2 layers * 2 sides * 128*128
            int l = gid >> 15, rem = gid & 32767, side = rem >> 14, cw = rem & 16383;
            int col = cw >> 7, k = cw & 127;
            const float* W = side ? Wr : Wl;
            Wt[gid] = (_Float16)W[l * 16384 + k * 128 + col];
        } else if (gid < 65536 + 256) {
            atth[gid - 65536] = (_Float16)att[gid - 65536];
        }
    }

    // ---- phase 1: per-tile histogram + rank (blocks 0..NTIL-1) ----
    if (b < NTIL) {
        if (t < NB) sh[t] = 0;
        __syncthreads();
        const int base = b * TS;
#pragma unroll
        for (int j = 0; j < TS / 1024; ++j) {
            int i = base + j * 1024 + t;
            if (i < E2) {
                int d = (i < E_EDGES) ? edge_dst[i] : (i - E_EDGES);
                int rk = atomicAdd(&sh[d >> 8], 1);
                rankbuf[i] = (unsigned short)rk;   // rank within (tile,bucket)
            }
        }
        __syncthreads();
        if (t < NB) tcnt[b * NB + t] = sh[t];
    }
    grid.sync();

    // ---- phase 2: per-bucket exclusive scan over tiles (strided buckets) ----
    for (int bk = b; bk < NB; bk += 256) {
        int v = (t < NTIL) ? tcnt[t * NB + bk] : 0;
        sh[t] = v;
        __syncthreads();
        for (int off = 1; off < 1024; off <<= 1) {
            int x = (t >= off) ? sh[t - off] : 0;
            __syncthreads();
            sh[t] += x;
            __syncthreads();
        }
        if (t < NTIL) toff[t * NB + bk] = sh[t] - v;   // exclusive
        if (t == 1023) bcnt[bk] = sh[1023];
        __syncthreads();
    }
    grid.sync();

    // ---- phase 3: scan bucket totals (block 0) ----
    if (b == 0) {
        int v = (t < NB) ? bcnt[t] : 0;
        sh[t] = v;
        __syncthreads();
        for (int off = 1; off < 1024; off <<= 1) {
            int x = (t >= off) ? sh[t - off] : 0;
            __syncthreads();
            sh[t] += x;
            __syncthreads();
        }
        if (t <= NB) bstart[t] = sh[t] - v;   // t==NB: total == E2
        if (t == 0) rowstart[N_NODES] = E2;
    }
    grid.sync();

    // ---- phase 4: atomic-free scatter into bucket-ordered pairbuf ----
    if (b < NTIL) {
        if (t < NB) sh[t] = bstart[t] + toff[b * NB + t];
        __syncthreads();
        const int tb = b * TS;
#pragma unroll
        for (int j = 0; j < TS / 1024; ++j) {
            int i = tb + j * 1024 + t;
            if (i < E2) {
                int d, sr;
                if (i < E_EDGES) { d = edge_dst[i]; sr = edge_src[i]; }
                else             { d = i - E_EDGES; sr = d; }
                int bk = d >> 8;
                pairbuf[sh[bk] + (int)rankbuf[i]] =
                    (unsigned)sr | ((unsigned)(d & 255) << 17);
            }
        }
    }
    grid.sync();

    // ---- phase 5: per-bucket node count+scan+scatter (strided buckets) ----
    for (int bk = b; bk < NB; bk += 256) {
        if (t < 256) sh[t] = 0;                       // cnt = sh[0..255]
        __syncthreads();
        const int e0 = bstart[bk], e1 = bstart[bk + 1];

        unsigned pr0, pr1, pr2, pr3, pr4, pr5, pr6, pr7;
        int rk0, rk1, rk2, rk3, rk4, rk5, rk6, rk7;
#define LOADP(K, PR)  { int p = e0 + t + (K) * 1024; PR = (p < e1) ? pairbuf[p] : 0u; }
        LOADP(0, pr0) LOADP(1, pr1) LOADP(2, pr2) LOADP(3, pr3)
        LOADP(4, pr4) LOADP(5, pr5) LOADP(6, pr6) LOADP(7, pr7)
#undef LOADP
#define HIST(K, PR, RK) { int p = e0 + t + (K) * 1024; \
        RK = (p < e1) ? atomicAdd(&sh[PR >> 17], 1) : 0; }
        HIST(0, pr0, rk0) HIST(1, pr1, rk1) HIST(2, pr2, rk2) HIST(3, pr3, rk3)
        HIST(4, pr4, rk4) HIST(5, pr5, rk5) HIST(6, pr6, rk6) HIST(7, pr7, rk7)
#undef HIST
        __syncthreads();

        int v = (t < 256) ? sh[t] : 0;                // sc = sh[256..511]
        if (t < 256) sh[256 + t] = v;
        __syncthreads();
        for (int o = 1; o < 256; o <<= 1) {
            int x = (t < 256 && t >= o) ? sh[256 + t - o] : 0;
            __syncthreads();
            if (t < 256) sh[256 + t] += x;
            __syncthreads();
        }
        if (t < 256) {
            int excl = sh[256 + t] - v;
            int node = (bk << 8) + t;
            if (node < N_NODES) rowstart[node] = e0 + excl;
            sh2[t] = e0 + excl;
        }
        __syncthreads();

#define SCAT(K, PR, RK) { int p = e0 + t + (K) * 1024; \
        if (p < e1) csr_src[sh2[PR >> 17] + RK] = (int)(PR & 0x1FFFF); }
        SCAT(0, pr0, rk0) SCAT(1, pr1, rk1) SCAT(2, pr2, rk2) SCAT(3, pr3, rk3)
        SCAT(4, pr4, rk4) SCAT(5, pr5, rk5) SCAT(6, pr6, rk6) SCAT(7, pr7, rk7)
#undef SCAT
        __syncthreads();                              // sh reused next bk
    }
}

// ---------------------------------------------------------------------------
// MFMA GEMM v14 (unchanged): 32-row waves + Wt panel staged in LDS with
// XOR swizzle (write+read same involution -> conflict-free ds_read_b128).
// ---------------------------------------------------------------------------
__global__ __launch_bounds__(256) void gemm_mfma5(
        const _Float16* __restrict__ hA,          // fp16 N x 128 (layer 1) or null
        const float* __restrict__ Afp,            // fp32 N x 128 (layer 0) or null
        const _Float16* __restrict__ Wt,          // fp16 [2][128][128] this layer
        _Float16* __restrict__ xl, _Float16* __restrict__ xr, int n_rows) {
    __shared__ char bsm[65536];                   // 256 rows x 256 B (exactly 64 KB)
    const int tid  = threadIdx.x;
    const int wave = tid >> 6;
    const int lane = tid & 63;
    const int m = lane & 15;
    const int q = lane >> 4;
    const int r0 = (blockIdx.x * 4 + wave) * 32;

    // ---- stage Wt panel -> LDS with XOR swizzle (16 chunks of 16B per thread)
#pragma unroll
    for (int k = 0; k < 16; ++k) {
        int ci  = tid + k * 256;                  // chunk index in [0, 4096)
        int row = ci >> 4;
        int off = (ci & 15) << 4;                 // byte offset within row
        uint4 v = *(const uint4*)((const char*)Wt + row * 256 + off);
        *(uint4*)(bsm + row * 256 + (off ^ ((row & 7) << 4))) = v;
    }
    __syncthreads();

    int arow0 = r0 + m;        if (arow0 >= n_rows) arow0 = n_rows - 1;
    int arow1 = r0 + 16 + m;   if (arow1 >= n_rows) arow1 = n_rows - 1;

    floatx4 acc[2][2][8];      // [side][rt][ct]
#pragma unroll
    for (int s = 0; s < 2; ++s)
#pragma unroll
        for (int rt = 0; rt < 2; ++rt)
#pragma unroll
            for (int ct = 0; ct < 8; ++ct) acc[s][rt][ct] = (floatx4){0.f,0.f,0.f,0.f};

    const int swz = (m & 7) << 4;                 // row&7 == m&7 (rows = ct*16+m)
#pragma unroll
    for (int ks = 0; ks < 4; ++ks) {
        const int k0 = ks * 32 + q * 8;
        const int cb = k0 * 2;                    // column byte offset
        h8 a0, a1;
        if (Afp) {
            float4 f0 = *(const float4*)(Afp + (size_t)arow0 * 128 + k0);
            float4 f1 = *(const float4*)(Afp + (size_t)arow0 * 128 + k0 + 4);
            float4 g0 = *(const float4*)(Afp + (size_t)arow1 * 128 + k0);
            float4 g1 = *(const float4*)(Afp + (size_t)arow1 * 128 + k0 + 4);
            a0 = (h8){(_Float16)f0.x, (_Float16)f0.y, (_Float16)f0.z, (_Float16)f0.w,
                      (_Float16)f1.x, (_Float16)f1.y, (_Float16)f1.z, (_Float16)f1.w};
            a1 = (h8){(_Float16)g0.x, (_Float16)g0.y, (_Float16)g0.z, (_Float16)g0.w,
                      (_Float16)g1.x, (_Float16)g1.y, (_Float16)g1.z, (_Float16)g1.w};
        } else {
            a0 = *(const h8*)(hA + (size_t)arow0 * 128 + k0);
            a1 = *(const h8*)(hA + (size_t)arow1 * 128 + k0);
        }
#pragma unroll
        for (int s = 0; s < 2; ++s) {
#pragma unroll
            for (int ct = 0; ct < 8; ++ct) {
                int row = s * 128 + ct * 16 + m;
                h8 bfrag = *(const h8*)(bsm + row * 256 + (cb ^ swz));
                acc[s][0][ct] = __builtin_amdgcn_mfma_f32_16x16x32_f16(a0, bfrag, acc[s][0][ct], 0, 0, 0);
                acc[s][1][ct] = __builtin_amdgcn_mfma_f32_16x16x32_f16(a1, bfrag, acc[s][1][ct], 0, 0, 0);
            }
        }
    }

#pragma unroll
    for (int s = 0; s < 2; ++s) {
        _Float16* out = s ? xr : xl;
#pragma unroll
        for (int rt = 0; rt < 2; ++rt)
#pragma unroll
            for (int ct = 0; ct < 8; ++ct)
#pragma unroll
                for (int i = 0; i < 4; ++i) {
                    int row = r0 + rt * 16 + q * 4 + i;
                    if (row < n_rows)
                        out[(size_t)row * 128 + ct * 16 + m] = (_Float16)acc[s][rt][ct][i];
                }
    }
}

// ---------------------------------------------------------------------------
// Fused per-node GATv2 (v10 structure, unchanged): zero LDS, 3-slot pipeline,
// shfl-butterfly epilogue, fp16 residual path between layers.
// ---------------------------------------------------------------------------
union U16 { uint4 u; h2 h[4]; };

__global__ __launch_bounds__(256) void gat_node10(
        const _Float16* __restrict__ xl,          // fp16 N x 128
        const _Float16* __restrict__ xr,          // fp16 N x 128
        const float* __restrict__ h_in_f32,       // layer 0: x, else null
        const _Float16* __restrict__ h_in_f16,    // layer 1: h16, else null
        const int* __restrict__ rowstart, const int* __restrict__ csr_src,
        const _Float16* __restrict__ atth, const float* __restrict__ bias,
        const float* __restrict__ gamma, const float* __restrict__ beta,
        float* __restrict__ out_f32,              // layer 1 output, else null
        _Float16* __restrict__ out_f16) {         // layer 0 output, else null
    const int wave = threadIdx.x >> 6;
    const int lane = threadIdx.x & 63;
    const int node = blockIdx.x * 4 + wave;       // grid exact: 25000*4
    const int esub = lane >> 3;
    const int r    = lane & 7;
    const int c0   = r * 16;
    const int c    = c0 + 2 * esub;               // output channel pair

    const int p0 = rowstart[node], p1 = rowstart[node + 1];
    const int pe = p1 - 1;                        // deg >= 1 (self-loop)

    U16 xra, xrb, ata, atb;
    {
        const uint4* xp = (const uint4*)(xr + (size_t)node * 128 + c0);
        xra.u = xp[0]; xrb.u = xp[1];
        const uint4* ap = (const uint4*)(atth + c0);
        ata.u = ap[0]; atb.u = ap[1];
    }
    const float2 bi = *(const float2*)(bias + c); // epilogue const, hoisted
    const h2 ns2 = {(_Float16)NEG_SLOPE, (_Float16)NEG_SLOPE};

    const unsigned short* xls = (const unsigned short*)xl;

    float s = 0.f;
    h2 acc2[8];
#pragma unroll
    for (int j = 0; j < 8; ++j) acc2[j] = (h2){(_Float16)0.f, (_Float16)0.f};

    // dot + weighted accumulate for one 8-edge batch (two indep FMA chains)
    auto consume = [&](const U16& u0, const U16& u1, bool v) {
        float da = 0.f, db = 0.f;
#pragma unroll
        for (int qq = 0; qq < 4; ++qq) {
            h2 z  = u0.h[qq] + xra.h[qq];
            h2 lk = __builtin_elementwise_max(z, z * ns2);
            da = fdot2f(lk, ata.h[qq], da);
        }
#pragma unroll
        for (int qq = 0; qq < 4; ++qq) {
            h2 z  = u1.h[qq] + xrb.h[qq];
            h2 lk = __builtin_elementwise_max(z, z * ns2);
            db = fdot2f(lk, atb.h[qq], db);
        }
        float d = da + db;
        float alpha = d + __shfl_xor(d, 1);        // half-head pair -> head dot
        float w = v ? __expf(alpha) : 0.f;
        s += w;
        h2 w2 = {(_Float16)w, (_Float16)w};
#pragma unroll
        for (int qq = 0; qq < 4; ++qq)
            acc2[qq] = w2 * u0.h[qq] + acc2[qq];
#pragma unroll
        for (int qq = 0; qq < 4; ++qq)
            acc2[qq + 4] = w2 * u1.h[qq] + acc2[qq + 4];
    };

    // ---- prologue: indices for batches 0,1,2; gathers for batches 0,1 ----
    int pA = p0 + esub;        if (pA > pe) pA = pe;
    int pB = p0 + 8 + esub;    if (pB > pe) pB = pe;
    int pC = p0 + 16 + esub;   if (pC > pe) pC = pe;
    int i0 = csr_src[pA];
    int i1 = csr_src[pB];
    int i2 = csr_src[pC];

    U16 s0a, s0b, s1a, s1b, s2a, s2b;
    { const uint4* rp = (const uint4*)(xls + (size_t)i0 * 128 + c0); s0a.u = rp[0]; s0b.u = rp[1]; }
    { const uint4* rp = (const uint4*)(xls + (size_t)i1 * 128 + c0); s1a.u = rp[0]; s1b.u = rp[1]; }

    int pb = p0;
    for (;;) {
        // ---- body 0: csr t+3 -> i0; gather t+2 via i2 -> slot2; consume slot0
        {
            int pn = pb + 24 + esub; if (pn > pe) pn = pe;
            int inew = csr_src[pn];                         // batch t+3 index
            if (pb + 16 < p1) {                             // wave-uniform
                const uint4* rp = (const uint4*)(xls + (size_t)i2 * 128 + c0);
                s2a.u = rp[0]; s2b.u = rp[1];
            }
            consume(s0a, s0b, (pb + esub) < p1);
            i0 = inew;
            pb += 8; if (pb >= p1) break;
        }
        // ---- body 1: csr t+3 -> i1; gather t+2 via i0 -> slot0; consume slot1
        {
            int pn = pb + 24 + esub; if (pn > pe) pn = pe;
            int inew = csr_src[pn];
            if (pb + 16 < p1) {
                const uint4* rp = (const uint4*)(xls + (size_t)i0 * 128 + c0);
                s0a.u = rp[0]; s0b.u = rp[1];
            }
            consume(s1a, s1b, (pb + esub) < p1);
            i1 = inew;
            pb += 8; if (pb >= p1) break;
        }
        // ---- body 2: csr t+3 -> i2; gather t+2 via i1 -> slot1; consume slot2
        {
            int pn = pb + 24 + esub; if (pn > pe) pn = pe;
            int inew = csr_src[pn];
            if (pb + 16 < p1) {
                const uint4* rp = (const uint4*)(xls + (size_t)i1 * 128 + c0);
                s1a.u = rp[0]; s1b.u = rp[1];
            }
            consume(s2a, s2b, (pb + esub) < p1);
            i2 = inew;
            pb += 8; if (pb >= p1) break;
        }
    }

    // ---- per-head softmax denominator: sum s across esub lanes ----
    float ssum = s;
    ssum += __shfl_xor(ssum, 8);
    ssum += __shfl_xor(ssum, 16);
    ssum += __shfl_xor(ssum, 32);
    // every lane now holds S for head (r>>1) == head of its output channels

    // ---- cross-esub butterfly reduction of acc2 (recursive halving) ----
    const bool sel0 = (esub & 1) != 0;
    const bool sel1 = ((esub >> 1) & 1) != 0;
    const bool sel2 = ((esub >> 2) & 1) != 0;
    h2 b4[4];
#pragma unroll
    for (int k = 0; k < 4; ++k) {
        h2 keep = sel0 ? acc2[2 * k + 1] : acc2[2 * k];
        h2 send = sel0 ? acc2[2 * k]     : acc2[2 * k + 1];
        b4[k] = keep + shfl_xor_h2(send, 8);
    }
    h2 c2[2];
#pragma unroll
    for (int k = 0; k < 2; ++k) {
        h2 keep = sel1 ? b4[2 * k + 1] : b4[2 * k];
        h2 send = sel1 ? b4[2 * k]     : b4[2 * k + 1];
        c2[k] = keep + shfl_xor_h2(send, 16);
    }
    h2 keepf = sel2 ? c2[1] : c2[0];
    h2 sendf = sel2 ? c2[0] : c2[1];
    h2 tot = keepf + shfl_xor_h2(sendf, 32);
    // tot = channels (c, c+1) summed over all 8 edge slots

    const float invS = 1.f / ssum;
    float g0 = (float)tot[0] * invS + bi.x;
    float g1 = (float)tot[1] * invS + bi.y;

    // issue remaining epilogue loads before the LN allreduce (latency cover)
    const float2 ga = *(const float2*)(gamma + c);
    const float2 be = *(const float2*)(beta + c);
    float hx, hy;
    if (h_in_f16) {
        h2 hv = *(const h2*)(h_in_f16 + (size_t)node * 128 + c);
        hx = (float)hv[0]; hy = (float)hv[1];
    } else {
        float2 hv = *(const float2*)(h_in_f32 + (size_t)node * 128 + c);
        hx = hv.x; hy = hv.y;
    }

    // ---- LayerNorm over 128 channels (full-wave allreduce) ----
    float sum = g0 + g1, sq = g0 * g0 + g1 * g1;
#pragma unroll
    for (int off = 1; off < 64; off <<= 1) {
        sum += __shfl_xor(sum, off);
        sq  += __shfl_xor(sq, off);
    }
    float mu   = sum * (1.f / 128.f);
    float var  = sq * (1.f / 128.f) - mu * mu;
    float rstd = rsqrtf(var + LN_EPS);
    float y0 = (g0 - mu) * rstd * ga.x + be.x;
    float y1 = (g1 - mu) * rstd * ga.y + be.y;
    float e0 = (y0 > 0.f) ? y0 : (__expf(y0) - 1.f);
    float e1 = (y1 > 0.f) ? y1 : (__expf(y1) - 1.f);

    float ox = hx + e0;
    float oy = hy + e1;
    if (out_f32) {
        float2 o; o.x = ox; o.y = oy;
        *(float2*)(out_f32 + (size_t)node * 128 + c) = o;
    } else {
        h2 po = {(_Float16)ox, (_Float16)oy};
        *(h2*)(out_f16 + (size_t)node * 128 + c) = po;
    }
}

// ---------------------------------------------------------------------------
extern "C" void kernel_launch(void* const* d_in, const int* in_sizes, int n_in,
                              void* d_out, int out_size, void* d_ws, size_t ws_size,
                              hipStream_t stream) {
    const float* x     = (const float*)d_in[0];
    const int*   eidx  = (const int*)d_in[1];   // (2, E)
    const float* Wl    = (const float*)d_in[2]; // (L,128,128)
    const float* Wr    = (const float*)d_in[3];
    const float* att   = (const float*)d_in[4]; // (L,4,32) -> stride 128
    const float* bias  = (const float*)d_in[5];
    const float* gamma = (const float*)d_in[6];
    const float* beta  = (const float*)d_in[7];
    float* out = (float*)d_out;

    char* ws = (char*)d_ws;
    _Float16* xl = (_Float16*)ws;              ws += (size_t)N_NODES * 128 * 2;
    _Float16* xr = (_Float16*)ws;              ws += (size_t)N_NODES * 128 * 2;
    _Float16* h16 = (_Float16*)ws;             ws += (size_t)N_NODES * 128 * 2;
    _Float16* Wt  = (_Float16*)ws;             ws += (size_t)65536 * 2;
    _Float16* atth = (_Float16*)ws;            ws += 256 * 2;
    unsigned* pairbuf = (unsigned*)ws;         ws += (size_t)E2 * 4;
    unsigned short* rankbuf = (unsigned short*)ws; ws += (size_t)E2 * 2;
    int* tcnt     = (int*)ws; ws += (size_t)NTIL * NB * 4;
    int* toff     = (int*)ws; ws += (size_t)NTIL * NB * 4;
    int* bcnt     = (int*)ws; ws += (NB + 1) * 4;
    int* bstart   = (int*)ws; ws += (NB + 1) * 4;
    int* rowstart = (int*)ws; ws += (size_t)(N_NODES + 4) * 4;
    int* csr_src  = (int*)ws; ws += (size_t)E2 * 4;

    const int* edge_src = eidx;
    const int* edge_dst = eidx + E_EDGES;

    // ---- fused prep + CSR build (single cooperative launch) ----
    void* cargs[] = {
        (void*)&edge_src, (void*)&edge_dst, (void*)&Wl, (void*)&Wr, (void*)&att,
        (void*)&Wt, (void*)&atth, (void*)&tcnt, (void*)&toff, (void*)&bcnt,
        (void*)&bstart, (void*)&rankbuf, (void*)&pairbuf, (void*)&rowstart,
        (void*)&csr_src
    };
    hipLaunchCooperativeKernel((void*)csr_fused, dim3(256), dim3(1024),
                               cargs, 0, stream);

    // ---- two GATv2 layers (fp16 intermediate h16 between them) ----
    const int gemm_gx = (N_NODES + 127) / 128;   // 782: 32 rows/wave, 4 waves/blk
    for (int l = 0; l < 2; ++l) {
        gemm_mfma5<<<gemm_gx, 256, 0, stream>>>(
            (l == 0) ? nullptr : h16, (l == 0) ? x : nullptr,
            Wt + (size_t)l * 32768, xl, xr, N_NODES);
        gat_node10<<<N_NODES / 4, 256, 0, stream>>>(
            xl, xr,
            (l == 0) ? x : nullptr, (l == 0) ? nullptr : h16,
            rowstart, csr_src,
            atth + l * 128, bias + l * 128, gamma + l * 128, beta + l * 128,
            (l == 1) ? out : nullptr, (l == 0) ? h16 : nullptr);
    }
}

// Round 12
// 357.027 us; speedup vs baseline: 1.4090x; 1.4090x over previous
//
#include <hip/hip_runtime.h>
#include <hip/hip_fp16.h>
#include <math.h>

#define N_NODES 100000
#define D_FEAT  128
#define E_EDGES 1600000
#define E2      (E_EDGES + N_NODES)   /* 1,700,000 with self-loops */
#define NEG_SLOPE 0.2f
#define LN_EPS    1e-5f

#define NB   391                      /* buckets of 256 nodes: d >> 8 */
#define TS   8192                     /* edges per tile */
#define NTIL ((E2 + TS - 1) / TS)     /* 208 */
#define PREPB 65                      /* prep blocks appended to tile_count */

typedef __attribute__((ext_vector_type(4))) float floatx4;
typedef _Float16 h2 __attribute__((ext_vector_type(2)));   // packed half pair
typedef _Float16 h8 __attribute__((ext_vector_type(8)));   // fp16 MFMA fragment

static __device__ __forceinline__ float fdot2f(h2 a, h2 b, float c) {
#if __has_builtin(__builtin_amdgcn_fdot2)
    return __builtin_amdgcn_fdot2(a, b, c, false);
#else
    return (float)a[0] * (float)b[0] + (float)a[1] * (float)b[1] + c;
#endif
}

static __device__ __forceinline__ h2 shfl_xor_h2(h2 v, int off) {
    int i = __builtin_bit_cast(int, v);
    i = __shfl_xor(i, off);
    return __builtin_bit_cast(h2, i);
}

// ---------------------------------------------------------------------------
// CSR build v16 (separate kernels -- v15 proved cooperative launch costs
// ~150us of graph overhead; fusing phases saves nothing since phases are
// internally latency-bound).  col_scan DELETED: tile_count reserves bucket
// space via 81k global atomicAdds (v11 calibration: ~5-10us) instead of the
// 391-block barrier-scan + tcnt round-trip.  bcnt zeroed by hipMemsetAsync.
// prep_wt rides along as extra blocks of tile_count's grid.
// ---------------------------------------------------------------------------
__global__ __launch_bounds__(1024) void tile_count_prep(
        const int* __restrict__ edge_dst,
        const float* __restrict__ Wl, const float* __restrict__ Wr,
        const float* __restrict__ att,
        _Float16* __restrict__ Wt, _Float16* __restrict__ atth,
        int* __restrict__ bcnt, int* __restrict__ toff,
        unsigned short* __restrict__ rankbuf) {
    const int b = blockIdx.x;
    const int t = threadIdx.x;
    if (b >= NTIL) {                      // ---- weight-prep blocks ----
        int gid = (b - NTIL) * 1024 + t;
        if (gid < 65536) {                // 2 layers * 2 sides * 128*128
            int l = gid >> 15, rem = gid & 32767, side = rem >> 14, cw = rem & 16383;
            int col = cw >> 7, k = cw & 127;
            const float* W = side ? Wr : Wl;
            Wt[gid] = (_Float16)W[l * 16384 + k * 128 + col];
        } else if (gid < 65536 + 256) {
            atth[gid - 65536] = (_Float16)att[gid - 65536];
        }
        return;
    }
    // ---- tile histogram + per-edge rank + bucket-space reservation ----
    __shared__ int h[NB];
    if (t < NB) h[t] = 0;
    __syncthreads();
    const int base = b * TS;
#pragma unroll
    for (int j = 0; j < TS / 1024; ++j) {
        int i = base + j * 1024 + t;
        if (i < E2) {
            int d = (i < E_EDGES) ? edge_dst[i] : (i - E_EDGES);
            int rk = atomicAdd(&h[d >> 8], 1);
            rankbuf[i] = (unsigned short)rk;  // rank within (tile,bucket)
        }
    }
    __syncthreads();
    if (t < NB) toff[b * NB + t] = atomicAdd(&bcnt[t], h[t]);  // reserve region
}

__global__ __launch_bounds__(512) void bucket_scan(const int* __restrict__ bcnt,
                                                   int* __restrict__ bstart,
                                                   int* __restrict__ rowstart) {
    __shared__ int s[512];
    const int t = threadIdx.x;
    int v = (t < NB) ? bcnt[t] : 0;
    s[t] = v;
    __syncthreads();
    for (int off = 1; off < 512; off <<= 1) {
        int x = (t >= off) ? s[t - off] : 0;
        __syncthreads();
        s[t] += x;
        __syncthreads();
    }
    if (t <= NB) bstart[t] = s[t] - v;   // t==NB: total == E2
    if (t == 0) rowstart[N_NODES] = E2;
}

__global__ __launch_bounds__(1024) void tile_scatter(const int* __restrict__ edge_src,
                                                     const int* __restrict__ edge_dst,
                                                     const int* __restrict__ bstart,
                                                     const int* __restrict__ toff,
                                                     const unsigned short* __restrict__ rankbuf,
                                                     unsigned* __restrict__ pairbuf) {
    __shared__ int base[NB];
    const int t = threadIdx.x;
    if (t < NB) base[t] = bstart[t] + toff[blockIdx.x * NB + t];
    __syncthreads();
    const int tb = blockIdx.x * TS;
#pragma unroll
    for (int j = 0; j < TS / 1024; ++j) {
        int i = tb + j * 1024 + t;
        if (i < E2) {
            int d, sr;
            if (i < E_EDGES) { d = edge_dst[i]; sr = edge_src[i]; }
            else             { d = i - E_EDGES; sr = d; }
            int b = d >> 8;
            int pos = base[b] + (int)rankbuf[i];            // no atomics
            pairbuf[pos] = (unsigned)sr | ((unsigned)(d & 255) << 17);
        }
    }
}

__global__ __launch_bounds__(1024) void bucketize(const unsigned* __restrict__ pairbuf,
                                                  const int* __restrict__ bstart,
                                                  int* __restrict__ rowstart,
                                                  int* __restrict__ csr_src) {
    __shared__ int cnt[256], off[256];
    const int blk = blockIdx.x;
    const int t = threadIdx.x;
    const int nbase = blk << 8;
    if (t < 256) cnt[t] = 0;
    __syncthreads();
    const int e0 = bstart[blk], e1 = bstart[blk + 1];

    // stage up to 8 edges per thread (max bucket ~4700 << 8192 capacity)
    unsigned pr0, pr1, pr2, pr3, pr4, pr5, pr6, pr7;
    int rk0, rk1, rk2, rk3, rk4, rk5, rk6, rk7;
#define LOADP(K, PR)  { int p = e0 + t + (K) * 1024; PR = (p < e1) ? pairbuf[p] : 0u; }
    LOADP(0, pr0) LOADP(1, pr1) LOADP(2, pr2) LOADP(3, pr3)
    LOADP(4, pr4) LOADP(5, pr5) LOADP(6, pr6) LOADP(7, pr7)
#undef LOADP
#define HIST(K, PR, RK) { int p = e0 + t + (K) * 1024; \
        RK = (p < e1) ? atomicAdd(&cnt[PR >> 17], 1) : 0; }
    HIST(0, pr0, rk0) HIST(1, pr1, rk1) HIST(2, pr2, rk2) HIST(3, pr3, rk3)
    HIST(4, pr4, rk4) HIST(5, pr5, rk5) HIST(6, pr6, rk6) HIST(7, pr7, rk7)
#undef HIST
    __syncthreads();

    // exclusive scan of the 256 per-node counts
    int v = (t < 256) ? cnt[t] : 0;
    __shared__ int sc[256];
    if (t < 256) sc[t] = v;
    __syncthreads();
    for (int o = 1; o < 256; o <<= 1) {
        int x = (t < 256 && t >= o) ? sc[t - o] : 0;
        __syncthreads();
        if (t < 256) sc[t] += x;
        __syncthreads();
    }
    if (t < 256) {
        int excl = sc[t] - v;
        int node = nbase + t;
        if (node < N_NODES) rowstart[node] = e0 + excl;
        off[t] = e0 + excl;
    }
    __syncthreads();

    // direct scatter using register-held (pair, rank)
#define SCAT(K, PR, RK) { int p = e0 + t + (K) * 1024; \
        if (p < e1) csr_src[off[PR >> 17] + RK] = (int)(PR & 0x1FFFF); }
    SCAT(0, pr0, rk0) SCAT(1, pr1, rk1) SCAT(2, pr2, rk2) SCAT(3, pr3, rk3)
    SCAT(4, pr4, rk4) SCAT(5, pr5, rk5) SCAT(6, pr6, rk6) SCAT(7, pr7, rk7)
#undef SCAT
}

// ---------------------------------------------------------------------------
// MFMA GEMM v14 (unchanged): 32-row waves + Wt panel staged in LDS with
// XOR swizzle (write+read same involution -> conflict-free ds_read_b128).
// ---------------------------------------------------------------------------
__global__ __launch_bounds__(256) void gemm_mfma5(
        const _Float16* __restrict__ hA,          // fp16 N x 128 (layer 1) or null
        const float* __restrict__ Afp,            // fp32 N x 128 (layer 0) or null
        const _Float16* __restrict__ Wt,          // fp16 [2][128][128] this layer
        _Float16* __restrict__ xl, _Float16* __restrict__ xr, int n_rows) {
    __shared__ char bsm[65536];                   // 256 rows x 256 B (exactly 64 KB)
    const int tid  = threadIdx.x;
    const int wave = tid >> 6;
    const int lane = tid & 63;
    const int m = lane & 15;
    const int q = lane >> 4;
    const int r0 = (blockIdx.x * 4 + wave) * 32;

    // ---- stage Wt panel -> LDS with XOR swizzle (16 chunks of 16B per thread)
#pragma unroll
    for (int k = 0; k < 16; ++k) {
        int ci  = tid + k * 256;                  // chunk index in [0, 4096)
        int row = ci >> 4;
        int off = (ci & 15) << 4;                 // byte offset within row
        uint4 v = *(const uint4*)((const char*)Wt + row * 256 + off);
        *(uint4*)(bsm + row * 256 + (off ^ ((row & 7) << 4))) = v;
    }
    __syncthreads();

    int arow0 = r0 + m;        if (arow0 >= n_rows) arow0 = n_rows - 1;
    int arow1 = r0 + 16 + m;   if (arow1 >= n_rows) arow1 = n_rows - 1;

    floatx4 acc[2][2][8];      // [side][rt][ct]
#pragma unroll
    for (int s = 0; s < 2; ++s)
#pragma unroll
        for (int rt = 0; rt < 2; ++rt)
#pragma unroll
            for (int ct = 0; ct < 8; ++ct) acc[s][rt][ct] = (floatx4){0.f,0.f,0.f,0.f};

    const int swz = (m & 7) << 4;                 // row&7 == m&7 (rows = ct*16+m)
#pragma unroll
    for (int ks = 0; ks < 4; ++ks) {
        const int k0 = ks * 32 + q * 8;
        const int cb = k0 * 2;                    // column byte offset
        h8 a0, a1;
        if (Afp) {
            float4 f0 = *(const float4*)(Afp + (size_t)arow0 * 128 + k0);
            float4 f1 = *(const float4*)(Afp + (size_t)arow0 * 128 + k0 + 4);
            float4 g0 = *(const float4*)(Afp + (size_t)arow1 * 128 + k0);
            float4 g1 = *(const float4*)(Afp + (size_t)arow1 * 128 + k0 + 4);
            a0 = (h8){(_Float16)f0.x, (_Float16)f0.y, (_Float16)f0.z, (_Float16)f0.w,
                      (_Float16)f1.x, (_Float16)f1.y, (_Float16)f1.z, (_Float16)f1.w};
            a1 = (h8){(_Float16)g0.x, (_Float16)g0.y, (_Float16)g0.z, (_Float16)g0.w,
                      (_Float16)g1.x, (_Float16)g1.y, (_Float16)g1.z, (_Float16)g1.w};
        } else {
            a0 = *(const h8*)(hA + (size_t)arow0 * 128 + k0);
            a1 = *(const h8*)(hA + (size_t)arow1 * 128 + k0);
        }
#pragma unroll
        for (int s = 0; s < 2; ++s) {
#pragma unroll
            for (int ct = 0; ct < 8; ++ct) {
                int row = s * 128 + ct * 16 + m;
                h8 bfrag = *(const h8*)(bsm + row * 256 + (cb ^ swz));
                acc[s][0][ct] = __builtin_amdgcn_mfma_f32_16x16x32_f16(a0, bfrag, acc[s][0][ct], 0, 0, 0);
                acc[s][1][ct] = __builtin_amdgcn_mfma_f32_16x16x32_f16(a1, bfrag, acc[s][1][ct], 0, 0, 0);
            }
        }
    }

#pragma unroll
    for (int s = 0; s < 2; ++s) {
        _Float16* out = s ? xr : xl;
#pragma unroll
        for (int rt = 0; rt < 2; ++rt)
#pragma unroll
            for (int ct = 0; ct < 8; ++ct)
#pragma unroll
                for (int i = 0; i < 4; ++i) {
                    int row = r0 + rt * 16 + q * 4 + i;
                    if (row < n_rows)
                        out[(size_t)row * 128 + ct * 16 + m] = (_Float16)acc[s][rt][ct][i];
                }
    }
}

// ---------------------------------------------------------------------------
// Fused per-node GATv2 (v10 structure, unchanged): zero LDS, 3-slot pipeline,
// shfl-butterfly epilogue, fp16 residual path between layers.
// ---------------------------------------------------------------------------
union U16 { uint4 u; h2 h[4]; };

__global__ __launch_bounds__(256) void gat_node10(
        const _Float16* __restrict__ xl,          // fp16 N x 128
        const _Float16* __restrict__ xr,          // fp16 N x 128
        const float* __restrict__ h_in_f32,       // layer 0: x, else null
        const _Float16* __restrict__ h_in_f16,    // layer 1: h16, else null
        const int* __restrict__ rowstart, const int* __restrict__ csr_src,
        const _Float16* __restrict__ atth, const float* __restrict__ bias,
        const float* __restrict__ gamma, const float* __restrict__ beta,
        float* __restrict__ out_f32,              // layer 1 output, else null
        _Float16* __restrict__ out_f16) {         // layer 0 output, else null
    const int wave = threadIdx.x >> 6;
    const int lane = threadIdx.x & 63;
    const int node = blockIdx.x * 4 + wave;       // grid exact: 25000*4
    const int esub = lane >> 3;
    const int r    = lane & 7;
    const int c0   = r * 16;
    const int c    = c0 + 2 * esub;               // output channel pair

    const int p0 = rowstart[node], p1 = rowstart[node + 1];
    const int pe = p1 - 1;                        // deg >= 1 (self-loop)

    U16 xra, xrb, ata, atb;
    {
        const uint4* xp = (const uint4*)(xr + (size_t)node * 128 + c0);
        xra.u = xp[0]; xrb.u = xp[1];
        const uint4* ap = (const uint4*)(atth + c0);
        ata.u = ap[0]; atb.u = ap[1];
    }
    const float2 bi = *(const float2*)(bias + c); // epilogue const, hoisted
    const h2 ns2 = {(_Float16)NEG_SLOPE, (_Float16)NEG_SLOPE};

    const unsigned short* xls = (const unsigned short*)xl;

    float s = 0.f;
    h2 acc2[8];
#pragma unroll
    for (int j = 0; j < 8; ++j) acc2[j] = (h2){(_Float16)0.f, (_Float16)0.f};

    // dot + weighted accumulate for one 8-edge batch (two indep FMA chains)
    auto consume = [&](const U16& u0, const U16& u1, bool v) {
        float da = 0.f, db = 0.f;
#pragma unroll
        for (int qq = 0; qq < 4; ++qq) {
            h2 z  = u0.h[qq] + xra.h[qq];
            h2 lk = __builtin_elementwise_max(z, z * ns2);
            da = fdot2f(lk, ata.h[qq], da);
        }
#pragma unroll
        for (int qq = 0; qq < 4; ++qq) {
            h2 z  = u1.h[qq] + xrb.h[qq];
            h2 lk = __builtin_elementwise_max(z, z * ns2);
            db = fdot2f(lk, atb.h[qq], db);
        }
        float d = da + db;
        float alpha = d + __shfl_xor(d, 1);        // half-head pair -> head dot
        float w = v ? __expf(alpha) : 0.f;
        s += w;
        h2 w2 = {(_Float16)w, (_Float16)w};
#pragma unroll
        for (int qq = 0; qq < 4; ++qq)
            acc2[qq] = w2 * u0.h[qq] + acc2[qq];
#pragma unroll
        for (int qq = 0; qq < 4; ++qq)
            acc2[qq + 4] = w2 * u1.h[qq] + acc2[qq + 4];
    };

    // ---- prologue: indices for batches 0,1,2; gathers for batches 0,1 ----
    int pA = p0 + esub;        if (pA > pe) pA = pe;
    int pB = p0 + 8 + esub;    if (pB > pe) pB = pe;
    int pC = p0 + 16 + esub;   if (pC > pe) pC = pe;
    int i0 = csr_src[pA];
    int i1 = csr_src[pB];
    int i2 = csr_src[pC];

    U16 s0a, s0b, s1a, s1b, s2a, s2b;
    { const uint4* rp = (const uint4*)(xls + (size_t)i0 * 128 + c0); s0a.u = rp[0]; s0b.u = rp[1]; }
    { const uint4* rp = (const uint4*)(xls + (size_t)i1 * 128 + c0); s1a.u = rp[0]; s1b.u = rp[1]; }

    int pb = p0;
    for (;;) {
        // ---- body 0: csr t+3 -> i0; gather t+2 via i2 -> slot2; consume slot0
        {
            int pn = pb + 24 + esub; if (pn > pe) pn = pe;
            int inew = csr_src[pn];                         // batch t+3 index
            if (pb + 16 < p1) {                             // wave-uniform
                const uint4* rp = (const uint4*)(xls + (size_t)i2 * 128 + c0);
                s2a.u = rp[0]; s2b.u = rp[1];
            }
            consume(s0a, s0b, (pb + esub) < p1);
            i0 = inew;
            pb += 8; if (pb >= p1) break;
        }
        // ---- body 1: csr t+3 -> i1; gather t+2 via i0 -> slot0; consume slot1
        {
            int pn = pb + 24 + esub; if (pn > pe) pn = pe;
            int inew = csr_src[pn];
            if (pb + 16 < p1) {
                const uint4* rp = (const uint4*)(xls + (size_t)i0 * 128 + c0);
                s0a.u = rp[0]; s0b.u = rp[1];
            }
            consume(s1a, s1b, (pb + esub) < p1);
            i1 = inew;
            pb += 8; if (pb >= p1) break;
        }
        // ---- body 2: csr t+3 -> i2; gather t+2 via i1 -> slot1; consume slot2
        {
            int pn = pb + 24 + esub; if (pn > pe) pn = pe;
            int inew = csr_src[pn];
            if (pb + 16 < p1) {
                const uint4* rp = (const uint4*)(xls + (size_t)i1 * 128 + c0);
                s1a.u = rp[0]; s1b.u = rp[1];
            }
            consume(s2a, s2b, (pb + esub) < p1);
            i2 = inew;
            pb += 8; if (pb >= p1) break;
        }
    }

    // ---- per-head softmax denominator: sum s across esub lanes ----
    float ssum = s;
    ssum += __shfl_xor(ssum, 8);
    ssum += __shfl_xor(ssum, 16);
    ssum += __shfl_xor(ssum, 32);
    // every lane now holds S for head (r>>1) == head of its output channels

    // ---- cross-esub butterfly reduction of acc2 (recursive halving) ----
    const bool sel0 = (esub & 1) != 0;
    const bool sel1 = ((esub >> 1) & 1) != 0;
    const bool sel2 = ((esub >> 2) & 1) != 0;
    h2 b4[4];
#pragma unroll
    for (int k = 0; k < 4; ++k) {
        h2 keep = sel0 ? acc2[2 * k + 1] : acc2[2 * k];
        h2 send = sel0 ? acc2[2 * k]     : acc2[2 * k + 1];
        b4[k] = keep + shfl_xor_h2(send, 8);
    }
    h2 c2[2];
#pragma unroll
    for (int k = 0; k < 2; ++k) {
        h2 keep = sel1 ? b4[2 * k + 1] : b4[2 * k];
        h2 send = sel1 ? b4[2 * k]     : b4[2 * k + 1];
        c2[k] = keep + shfl_xor_h2(send, 16);
    }
    h2 keepf = sel2 ? c2[1] : c2[0];
    h2 sendf = sel2 ? c2[0] : c2[1];
    h2 tot = keepf + shfl_xor_h2(sendf, 32);
    // tot = channels (c, c+1) summed over all 8 edge slots

    const float invS = 1.f / ssum;
    float g0 = (float)tot[0] * invS + bi.x;
    float g1 = (float)tot[1] * invS + bi.y;

    // issue remaining epilogue loads before the LN allreduce (latency cover)
    const float2 ga = *(const float2*)(gamma + c);
    const float2 be = *(const float2*)(beta + c);
    float hx, hy;
    if (h_in_f16) {
        h2 hv = *(const h2*)(h_in_f16 + (size_t)node * 128 + c);
        hx = (float)hv[0]; hy = (float)hv[1];
    } else {
        float2 hv = *(const float2*)(h_in_f32 + (size_t)node * 128 + c);
        hx = hv.x; hy = hv.y;
    }

    // ---- LayerNorm over 128 channels (full-wave allreduce) ----
    float sum = g0 + g1, sq = g0 * g0 + g1 * g1;
#pragma unroll
    for (int off = 1; off < 64; off <<= 1) {
        sum += __shfl_xor(sum, off);
        sq  += __shfl_xor(sq, off);
    }
    float mu   = sum * (1.f / 128.f);
    float var  = sq * (1.f / 128.f) - mu * mu;
    float rstd = rsqrtf(var + LN_EPS);
    float y0 = (g0 - mu) * rstd * ga.x + be.x;
    float y1 = (g1 - mu) * rstd * ga.y + be.y;
    float e0 = (y0 > 0.f) ? y0 : (__expf(y0) - 1.f);
    float e1 = (y1 > 0.f) ? y1 : (__expf(y1) - 1.f);

    float ox = hx + e0;
    float oy = hy + e1;
    if (out_f32) {
        float2 o; o.x = ox; o.y = oy;
        *(float2*)(out_f32 + (size_t)node * 128 + c) = o;
    } else {
        h2 po = {(_Float16)ox, (_Float16)oy};
        *(h2*)(out_f16 + (size_t)node * 128 + c) = po;
    }
}

// ---------------------------------------------------------------------------
extern "C" void kernel_launch(void* const* d_in, const int* in_sizes, int n_in,
                              void* d_out, int out_size, void* d_ws, size_t ws_size,
                              hipStream_t stream) {
    const float* x     = (const float*)d_in[0];
    const int*   eidx  = (const int*)d_in[1];   // (2, E)
    const float* Wl    = (const float*)d_in[2]; // (L,128,128)
    const float* Wr    = (const float*)d_in[3];
    const float* att   = (const float*)d_in[4]; // (L,4,32) -> stride 128
    const float* bias  = (const float*)d_in[5];
    const float* gamma = (const float*)d_in[6];
    const float* beta  = (const float*)d_in[7];
    float* out = (float*)d_out;

    char* ws = (char*)d_ws;
    _Float16* xl = (_Float16*)ws;              ws += (size_t)N_NODES * 128 * 2;
    _Float16* xr = (_Float16*)ws;              ws += (size_t)N_NODES * 128 * 2;
    _Float16* h16 = (_Float16*)ws;             ws += (size_t)N_NODES * 128 * 2;
    _Float16* Wt  = (_Float16*)ws;             ws += (size_t)65536 * 2;
    _Float16* atth = (_Float16*)ws;            ws += 256 * 2;
    unsigned* pairbuf = (unsigned*)ws;         ws += (size_t)E2 * 4;
    unsigned short* rankbuf = (unsigned short*)ws; ws += (size_t)E2 * 2;
    int* toff     = (int*)ws; ws += (size_t)NTIL * NB * 4;
    int* bcnt     = (int*)ws; ws += (NB + 1) * 4;
    int* bstart   = (int*)ws; ws += (NB + 1) * 4;
    int* rowstart = (int*)ws; ws += (size_t)(N_NODES + 4) * 4;
    int* csr_src  = (int*)ws; ws += (size_t)E2 * 4;

    const int* edge_src = eidx;
    const int* edge_dst = eidx + E_EDGES;

    // ---- CSR build (radix, col_scan replaced by atomic reservation) ----
    hipMemsetAsync(bcnt, 0, (NB + 1) * sizeof(int), stream);
    tile_count_prep<<<NTIL + PREPB, 1024, 0, stream>>>(
        edge_dst, Wl, Wr, att, Wt, atth, bcnt, toff, rankbuf);
    bucket_scan<<<1, 512, 0, stream>>>(bcnt, bstart, rowstart);
    tile_scatter<<<NTIL, 1024, 0, stream>>>(edge_src, edge_dst, bstart, toff,
                                            rankbuf, pairbuf);
    bucketize<<<NB, 1024, 0, stream>>>(pairbuf, bstart, rowstart, csr_src);

    // ---- two GATv2 layers (fp16 intermediate h16 between them) ----
    const int gemm_gx = (N_NODES + 127) / 128;   // 782: 32 rows/wave, 4 waves/blk
    for (int l = 0; l < 2; ++l) {
        gemm_mfma5<<<gemm_gx, 256, 0, stream>>>(
            (l == 0) ? nullptr : h16, (l == 0) ? x : nullptr,
            Wt + (size_t)l * 32768, xl, xr, N_NODES);
        gat_node10<<<N_NODES / 4, 256, 0, stream>>>(
            xl, xr,
            (l == 0) ? x : nullptr, (l == 0) ? nullptr : h16,
            rowstart, csr_src,
            atth + l * 128, bias + l * 128, gamma + l * 128, beta + l * 128,
            (l == 1) ? out : nullptr, (l == 0) ? h16 : nullptr);
    }
}

// Round 13
// 356.510 us; speedup vs baseline: 1.4110x; 1.0015x over previous
//
#include <hip/hip_runtime.h>
#include <hip/hip_fp16.h>
#include <math.h>

#define N_NODES 100000
#define D_FEAT  128
#define E_EDGES 1600000
#define E2      (E_EDGES + N_NODES)   /* 1,700,000 with self-loops */
#define NEG_SLOPE 0.2f
#define LN_EPS    1e-5f

#define NB   391                      /* buckets of 256 nodes: d >> 8 */
#define TS   8192                     /* edges per tile */
#define NTIL ((E2 + TS - 1) / TS)     /* 208 */
#define PREPB 65                      /* prep blocks appended to count_scatter */
#define MAXB 8192                     /* fixed pairbuf region per bucket;
                                         occupancy 4348 +- 66 -> +58 sigma margin */

typedef __attribute__((ext_vector_type(4))) float floatx4;
typedef _Float16 h2 __attribute__((ext_vector_type(2)));   // packed half pair
typedef _Float16 h8 __attribute__((ext_vector_type(8)));   // fp16 MFMA fragment

static __device__ __forceinline__ float fdot2f(h2 a, h2 b, float c) {
#if __has_builtin(__builtin_amdgcn_fdot2)
    return __builtin_amdgcn_fdot2(a, b, c, false);
#else
    return (float)a[0] * (float)b[0] + (float)a[1] * (float)b[1] + c;
#endif
}

static __device__ __forceinline__ h2 shfl_xor_h2(h2 v, int off) {
    int i = __builtin_bit_cast(int, v);
    i = __shfl_xor(i, off);
    return __builtin_bit_cast(h2, i);
}

// ---------------------------------------------------------------------------
// CSR build v17: dependency-minimal chain = memset + 2 kernels.
//  count_scatter_prep: per-tile LDS hist (rank kept in regs, d|rank<<17),
//    bucket-space reservation via global atomicAdd (v16 trick), scatter to
//    FIXED region k*MAXB + toff + rank -- no bstart dependency, no rankbuf,
//    no second edge read.  prep_wt rides along as extra blocks.
//  bucketize2: fixed-region input; computes the 391-value global-offset scan
//    redundantly per block (kills the serial bucket_scan kernel + 2 launch
//    boundaries).
// ---------------------------------------------------------------------------
__global__ __launch_bounds__(1024) void count_scatter_prep(
        const int* __restrict__ edge_src, const int* __restrict__ edge_dst,
        const float* __restrict__ Wl, const float* __restrict__ Wr,
        const float* __restrict__ att,
        _Float16* __restrict__ Wt, _Float16* __restrict__ atth,
        int* __restrict__ bcnt, unsigned* __restrict__ pairbuf) {
    const int b = blockIdx.x;
    const int t = threadIdx.x;
    if (b >= NTIL) {                      // ---- weight-prep blocks ----
        int gid = (b - NTIL) * 1024 + t;
        if (gid < 65536) {                // 2 layers * 2 sides * 128*128
            int l = gid >> 15, rem = gid & 32767, side = rem >> 14, cw = rem & 16383;
            int col = cw >> 7, k = cw & 127;
            const float* W = side ? Wr : Wl;
            Wt[gid] = (_Float16)W[l * 16384 + k * 128 + col];
        } else if (gid < 65536 + 256) {
            atth[gid - 65536] = (_Float16)att[gid - 65536];
        }
        return;
    }
    __shared__ int h[NB];
    __shared__ int base[NB];
    if (t < NB) h[t] = 0;
    __syncthreads();
    const int tb = b * TS;
    int pk[8];                            // d | rank<<17 (d<2^17, rank<2^13)
#pragma unroll
    for (int j = 0; j < 8; ++j) {
        int i = tb + j * 1024 + t;
        int d = 0, rk = 0;
        if (i < E2) {
            d = (i < E_EDGES) ? edge_dst[i] : (i - E_EDGES);
            rk = atomicAdd(&h[d >> 8], 1);
        }
        pk[j] = d | (rk << 17);
    }
    __syncthreads();
    if (t < NB) base[t] = t * MAXB + atomicAdd(&bcnt[t], h[t]);  // reservation
    __syncthreads();
#pragma unroll
    for (int j = 0; j < 8; ++j) {
        int i = tb + j * 1024 + t;
        if (i < E2) {
            int d  = pk[j] & 0x1FFFF;
            int rk = pk[j] >> 17;
            int sr = (i < E_EDGES) ? edge_src[i] : d;   // self-loop: sr = d
            pairbuf[base[d >> 8] + rk] =
                (unsigned)sr | ((unsigned)(d & 255) << 17);
        }
    }
}

__global__ __launch_bounds__(1024) void bucketize2(
        const unsigned* __restrict__ pairbuf, const int* __restrict__ bcnt,
        int* __restrict__ rowstart, int* __restrict__ csr_src) {
    __shared__ int s[512];
    __shared__ int cnt[256], off[256];
    const int blk = blockIdx.x;
    const int t = threadIdx.x;

    // ---- redundant exclusive scan of bcnt -> this bucket's global start ----
    if (t < 512) s[t] = (t < NB) ? bcnt[t] : 0;
    __syncthreads();
    for (int o = 1; o < 512; o <<= 1) {
        int x = (t < 512 && t >= o) ? s[t - o] : 0;
        __syncthreads();
        if (t < 512) s[t] += x;
        __syncthreads();
    }
    const int count = bcnt[blk];
    const int g0 = s[blk] - count;        // exclusive prefix = global start
    const int e0 = blk * MAXB;            // fixed pairbuf region
    const int nbase = blk << 8;
    if (t < 256) cnt[t] = 0;
    __syncthreads();                      // also fences the s[blk] reads

    // stage up to 8 edges per thread (count ~4350 << 8192 capacity)
    unsigned pr0, pr1, pr2, pr3, pr4, pr5, pr6, pr7;
    int rk0, rk1, rk2, rk3, rk4, rk5, rk6, rk7;
#define LOADP(K, PR)  { int p = t + (K) * 1024; PR = (p < count) ? pairbuf[e0 + p] : 0u; }
    LOADP(0, pr0) LOADP(1, pr1) LOADP(2, pr2) LOADP(3, pr3)
    LOADP(4, pr4) LOADP(5, pr5) LOADP(6, pr6) LOADP(7, pr7)
#undef LOADP
#define HIST(K, PR, RK) { int p = t + (K) * 1024; \
        RK = (p < count) ? atomicAdd(&cnt[PR >> 17], 1) : 0; }
    HIST(0, pr0, rk0) HIST(1, pr1, rk1) HIST(2, pr2, rk2) HIST(3, pr3, rk3)
    HIST(4, pr4, rk4) HIST(5, pr5, rk5) HIST(6, pr6, rk6) HIST(7, pr7, rk7)
#undef HIST
    __syncthreads();

    // exclusive scan of the 256 per-node counts (reuse s[0..255])
    int v = (t < 256) ? cnt[t] : 0;
    if (t < 256) s[t] = v;
    __syncthreads();
    for (int o = 1; o < 256; o <<= 1) {
        int x = (t < 256 && t >= o) ? s[t - o] : 0;
        __syncthreads();
        if (t < 256) s[t] += x;
        __syncthreads();
    }
    if (t < 256) {
        int excl = s[t] - v;
        int node = nbase + t;
        if (node < N_NODES) rowstart[node] = g0 + excl;
        off[t] = g0 + excl;
    }
    if (blk == 0 && t == 0) rowstart[N_NODES] = E2;
    __syncthreads();

    // direct scatter using register-held (pair, rank)
#define SCAT(K, PR, RK) { int p = t + (K) * 1024; \
        if (p < count) csr_src[off[PR >> 17] + RK] = (int)(PR & 0x1FFFF); }
    SCAT(0, pr0, rk0) SCAT(1, pr1, rk1) SCAT(2, pr2, rk2) SCAT(3, pr3, rk3)
    SCAT(4, pr4, rk4) SCAT(5, pr5, rk5) SCAT(6, pr6, rk6) SCAT(7, pr7, rk7)
#undef SCAT
}

// ---------------------------------------------------------------------------
// MFMA GEMM v14 (unchanged): 32-row waves + Wt panel staged in LDS with
// XOR swizzle (write+read same involution -> conflict-free ds_read_b128).
// ---------------------------------------------------------------------------
__global__ __launch_bounds__(256) void gemm_mfma5(
        const _Float16* __restrict__ hA,          // fp16 N x 128 (layer 1) or null
        const float* __restrict__ Afp,            // fp32 N x 128 (layer 0) or null
        const _Float16* __restrict__ Wt,          // fp16 [2][128][128] this layer
        _Float16* __restrict__ xl, _Float16* __restrict__ xr, int n_rows) {
    __shared__ char bsm[65536];                   // 256 rows x 256 B (exactly 64 KB)
    const int tid  = threadIdx.x;
    const int wave = tid >> 6;
    const int lane = tid & 63;
    const int m = lane & 15;
    const int q = lane >> 4;
    const int r0 = (blockIdx.x * 4 + wave) * 32;

    // ---- stage Wt panel -> LDS with XOR swizzle (16 chunks of 16B per thread)
#pragma unroll
    for (int k = 0; k < 16; ++k) {
        int ci  = tid + k * 256;                  // chunk index in [0, 4096)
        int row = ci >> 4;
        int off = (ci & 15) << 4;                 // byte offset within row
        uint4 v = *(const uint4*)((const char*)Wt + row * 256 + off);
        *(uint4*)(bsm + row * 256 + (off ^ ((row & 7) << 4))) = v;
    }
    __syncthreads();

    int arow0 = r0 + m;        if (arow0 >= n_rows) arow0 = n_rows - 1;
    int arow1 = r0 + 16 + m;   if (arow1 >= n_rows) arow1 = n_rows - 1;

    floatx4 acc[2][2][8];      // [side][rt][ct]
#pragma unroll
    for (int s = 0; s < 2; ++s)
#pragma unroll
        for (int rt = 0; rt < 2; ++rt)
#pragma unroll
            for (int ct = 0; ct < 8; ++ct) acc[s][rt][ct] = (floatx4){0.f,0.f,0.f,0.f};

    const int swz = (m & 7) << 4;                 // row&7 == m&7 (rows = ct*16+m)
#pragma unroll
    for (int ks = 0; ks < 4; ++ks) {
        const int k0 = ks * 32 + q * 8;
        const int cb = k0 * 2;                    // column byte offset
        h8 a0, a1;
        if (Afp) {
            float4 f0 = *(const float4*)(Afp + (size_t)arow0 * 128 + k0);
            float4 f1 = *(const float4*)(Afp + (size_t)arow0 * 128 + k0 + 4);
            float4 g0 = *(const float4*)(Afp + (size_t)arow1 * 128 + k0);
            float4 g1 = *(const float4*)(Afp + (size_t)arow1 * 128 + k0 + 4);
            a0 = (h8){(_Float16)f0.x, (_Float16)f0.y, (_Float16)f0.z, (_Float16)f0.w,
                      (_Float16)f1.x, (_Float16)f1.y, (_Float16)f1.z, (_Float16)f1.w};
            a1 = (h8){(_Float16)g0.x, (_Float16)g0.y, (_Float16)g0.z, (_Float16)g0.w,
                      (_Float16)g1.x, (_Float16)g1.y, (_Float16)g1.z, (_Float16)g1.w};
        } else {
            a0 = *(const h8*)(hA + (size_t)arow0 * 128 + k0);
            a1 = *(const h8*)(hA + (size_t)arow1 * 128 + k0);
        }
#pragma unroll
        for (int s = 0; s < 2; ++s) {
#pragma unroll
            for (int ct = 0; ct < 8; ++ct) {
                int row = s * 128 + ct * 16 + m;
                h8 bfrag = *(const h8*)(bsm + row * 256 + (cb ^ swz));
                acc[s][0][ct] = __builtin_amdgcn_mfma_f32_16x16x32_f16(a0, bfrag, acc[s][0][ct], 0, 0, 0);
                acc[s][1][ct] = __builtin_amdgcn_mfma_f32_16x16x32_f16(a1, bfrag, acc[s][1][ct], 0, 0, 0);
            }
        }
    }

#pragma unroll
    for (int s = 0; s < 2; ++s) {
        _Float16* out = s ? xr : xl;
#pragma unroll
        for (int rt = 0; rt < 2; ++rt)
#pragma unroll
            for (int ct = 0; ct < 8; ++ct)
#pragma unroll
                for (int i = 0; i < 4; ++i) {
                    int row = r0 + rt * 16 + q * 4 + i;
                    if (row < n_rows)
                        out[(size_t)row * 128 + ct * 16 + m] = (_Float16)acc[s][rt][ct][i];
                }
    }
}

// ---------------------------------------------------------------------------
// Fused per-node GATv2 (v10 structure, unchanged): zero LDS, 3-slot pipeline,
// shfl-butterfly epilogue, fp16 residual path between layers.
// ---------------------------------------------------------------------------
union U16 { uint4 u; h2 h[4]; };

__global__ __launch_bounds__(256) void gat_node10(
        const _Float16* __restrict__ xl,          // fp16 N x 128
        const _Float16* __restrict__ xr,          // fp16 N x 128
        const float* __restrict__ h_in_f32,       // layer 0: x, else null
        const _Float16* __restrict__ h_in_f16,    // layer 1: h16, else null
        const int* __restrict__ rowstart, const int* __restrict__ csr_src,
        const _Float16* __restrict__ atth, const float* __restrict__ bias,
        const float* __restrict__ gamma, const float* __restrict__ beta,
        float* __restrict__ out_f32,              // layer 1 output, else null
        _Float16* __restrict__ out_f16) {         // layer 0 output, else null
    const int wave = threadIdx.x >> 6;
    const int lane = threadIdx.x & 63;
    const int node = blockIdx.x * 4 + wave;       // grid exact: 25000*4
    const int esub = lane >> 3;
    const int r    = lane & 7;
    const int c0   = r * 16;
    const int c    = c0 + 2 * esub;               // output channel pair

    const int p0 = rowstart[node], p1 = rowstart[node + 1];
    const int pe = p1 - 1;                        // deg >= 1 (self-loop)

    U16 xra, xrb, ata, atb;
    {
        const uint4* xp = (const uint4*)(xr + (size_t)node * 128 + c0);
        xra.u = xp[0]; xrb.u = xp[1];
        const uint4* ap = (const uint4*)(atth + c0);
        ata.u = ap[0]; atb.u = ap[1];
    }
    const float2 bi = *(const float2*)(bias + c); // epilogue const, hoisted
    const h2 ns2 = {(_Float16)NEG_SLOPE, (_Float16)NEG_SLOPE};

    const unsigned short* xls = (const unsigned short*)xl;

    float s = 0.f;
    h2 acc2[8];
#pragma unroll
    for (int j = 0; j < 8; ++j) acc2[j] = (h2){(_Float16)0.f, (_Float16)0.f};

    // dot + weighted accumulate for one 8-edge batch (two indep FMA chains)
    auto consume = [&](const U16& u0, const U16& u1, bool v) {
        float da = 0.f, db = 0.f;
#pragma unroll
        for (int qq = 0; qq < 4; ++qq) {
            h2 z  = u0.h[qq] + xra.h[qq];
            h2 lk = __builtin_elementwise_max(z, z * ns2);
            da = fdot2f(lk, ata.h[qq], da);
        }
#pragma unroll
        for (int qq = 0; qq < 4; ++qq) {
            h2 z  = u1.h[qq] + xrb.h[qq];
            h2 lk = __builtin_elementwise_max(z, z * ns2);
            db = fdot2f(lk, atb.h[qq], db);
        }
        float d = da + db;
        float alpha = d + __shfl_xor(d, 1);        // half-head pair -> head dot
        float w = v ? __expf(alpha) : 0.f;
        s += w;
        h2 w2 = {(_Float16)w, (_Float16)w};
#pragma unroll
        for (int qq = 0; qq < 4; ++qq)
            acc2[qq] = w2 * u0.h[qq] + acc2[qq];
#pragma unroll
        for (int qq = 0; qq < 4; ++qq)
            acc2[qq + 4] = w2 * u1.h[qq] + acc2[qq + 4];
    };

    // ---- prologue: indices for batches 0,1,2; gathers for batches 0,1 ----
    int pA = p0 + esub;        if (pA > pe) pA = pe;
    int pB = p0 + 8 + esub;    if (pB > pe) pB = pe;
    int pC = p0 + 16 + esub;   if (pC > pe) pC = pe;
    int i0 = csr_src[pA];
    int i1 = csr_src[pB];
    int i2 = csr_src[pC];

    U16 s0a, s0b, s1a, s1b, s2a, s2b;
    { const uint4* rp = (const uint4*)(xls + (size_t)i0 * 128 + c0); s0a.u = rp[0]; s0b.u = rp[1]; }
    { const uint4* rp = (const uint4*)(xls + (size_t)i1 * 128 + c0); s1a.u = rp[0]; s1b.u = rp[1]; }

    int pb = p0;
    for (;;) {
        // ---- body 0: csr t+3 -> i0; gather t+2 via i2 -> slot2; consume slot0
        {
            int pn = pb + 24 + esub; if (pn > pe) pn = pe;
            int inew = csr_src[pn];                         // batch t+3 index
            if (pb + 16 < p1) {                             // wave-uniform
                const uint4* rp = (const uint4*)(xls + (size_t)i2 * 128 + c0);
                s2a.u = rp[0]; s2b.u = rp[1];
            }
            consume(s0a, s0b, (pb + esub) < p1);
            i0 = inew;
            pb += 8; if (pb >= p1) break;
        }
        // ---- body 1: csr t+3 -> i1; gather t+2 via i0 -> slot0; consume slot1
        {
            int pn = pb + 24 + esub; if (pn > pe) pn = pe;
            int inew = csr_src[pn];
            if (pb + 16 < p1) {
                const uint4* rp = (const uint4*)(xls + (size_t)i0 * 128 + c0);
                s0a.u = rp[0]; s0b.u = rp[1];
            }
            consume(s1a, s1b, (pb + esub) < p1);
            i1 = inew;
            pb += 8; if (pb >= p1) break;
        }
        // ---- body 2: csr t+3 -> i2; gather t+2 via i1 -> slot1; consume slot2
        {
            int pn = pb + 24 + esub; if (pn > pe) pn = pe;
            int inew = csr_src[pn];
            if (pb + 16 < p1) {
                const uint4* rp = (const uint4*)(xls + (size_t)i1 * 128 + c0);
                s1a.u = rp[0]; s1b.u = rp[1];
            }
            consume(s2a, s2b, (pb + esub) < p1);
            i2 = inew;
            pb += 8; if (pb >= p1) break;
        }
    }

    // ---- per-head softmax denominator: sum s across esub lanes ----
    float ssum = s;
    ssum += __shfl_xor(ssum, 8);
    ssum += __shfl_xor(ssum, 16);
    ssum += __shfl_xor(ssum, 32);
    // every lane now holds S for head (r>>1) == head of its output channels

    // ---- cross-esub butterfly reduction of acc2 (recursive halving) ----
    const bool sel0 = (esub & 1) != 0;
    const bool sel1 = ((esub >> 1) & 1) != 0;
    const bool sel2 = ((esub >> 2) & 1) != 0;
    h2 b4[4];
#pragma unroll
    for (int k = 0; k < 4; ++k) {
        h2 keep = sel0 ? acc2[2 * k + 1] : acc2[2 * k];
        h2 send = sel0 ? acc2[2 * k]     : acc2[2 * k + 1];
        b4[k] = keep + shfl_xor_h2(send, 8);
    }
    h2 c2[2];
#pragma unroll
    for (int k = 0; k < 2; ++k) {
        h2 keep = sel1 ? b4[2 * k + 1] : b4[2 * k];
        h2 send = sel1 ? b4[2 * k]     : b4[2 * k + 1];
        c2[k] = keep + shfl_xor_h2(send, 16);
    }
    h2 keepf = sel2 ? c2[1] : c2[0];
    h2 sendf = sel2 ? c2[0] : c2[1];
    h2 tot = keepf + shfl_xor_h2(sendf, 32);
    // tot = channels (c, c+1) summed over all 8 edge slots

    const float invS = 1.f / ssum;
    float g0 = (float)tot[0] * invS + bi.x;
    float g1 = (float)tot[1] * invS + bi.y;

    // issue remaining epilogue loads before the LN allreduce (latency cover)
    const float2 ga = *(const float2*)(gamma + c);
    const float2 be = *(const float2*)(beta + c);
    float hx, hy;
    if (h_in_f16) {
        h2 hv = *(const h2*)(h_in_f16 + (size_t)node * 128 + c);
        hx = (float)hv[0]; hy = (float)hv[1];
    } else {
        float2 hv = *(const float2*)(h_in_f32 + (size_t)node * 128 + c);
        hx = hv.x; hy = hv.y;
    }

    // ---- LayerNorm over 128 channels (full-wave allreduce) ----
    float sum = g0 + g1, sq = g0 * g0 + g1 * g1;
#pragma unroll
    for (int off = 1; off < 64; off <<= 1) {
        sum += __shfl_xor(sum, off);
        sq  += __shfl_xor(sq, off);
    }
    float mu   = sum * (1.f / 128.f);
    float var  = sq * (1.f / 128.f) - mu * mu;
    float rstd = rsqrtf(var + LN_EPS);
    float y0 = (g0 - mu) * rstd * ga.x + be.x;
    float y1 = (g1 - mu) * rstd * ga.y + be.y;
    float e0 = (y0 > 0.f) ? y0 : (__expf(y0) - 1.f);
    float e1 = (y1 > 0.f) ? y1 : (__expf(y1) - 1.f);

    float ox = hx + e0;
    float oy = hy + e1;
    if (out_f32) {
        float2 o; o.x = ox; o.y = oy;
        *(float2*)(out_f32 + (size_t)node * 128 + c) = o;
    } else {
        h2 po = {(_Float16)ox, (_Float16)oy};
        *(h2*)(out_f16 + (size_t)node * 128 + c) = po;
    }
}

// ---------------------------------------------------------------------------
extern "C" void kernel_launch(void* const* d_in, const int* in_sizes, int n_in,
                              void* d_out, int out_size, void* d_ws, size_t ws_size,
                              hipStream_t stream) {
    const float* x     = (const float*)d_in[0];
    const int*   eidx  = (const int*)d_in[1];   // (2, E)
    const float* Wl    = (const float*)d_in[2]; // (L,128,128)
    const float* Wr    = (const float*)d_in[3];
    const float* att   = (const float*)d_in[4]; // (L,4,32) -> stride 128
    const float* bias  = (const float*)d_in[5];
    const float* gamma = (const float*)d_in[6];
    const float* beta  = (const float*)d_in[7];
    float* out = (float*)d_out;

    char* ws = (char*)d_ws;
    _Float16* xl = (_Float16*)ws;              ws += (size_t)N_NODES * 128 * 2;
    _Float16* xr = (_Float16*)ws;              ws += (size_t)N_NODES * 128 * 2;
    _Float16* h16 = (_Float16*)ws;             ws += (size_t)N_NODES * 128 * 2;
    _Float16* Wt  = (_Float16*)ws;             ws += (size_t)65536 * 2;
    _Float16* atth = (_Float16*)ws;            ws += 256 * 2;
    unsigned* pairbuf = (unsigned*)ws;         ws += (size_t)NB * MAXB * 4;
    int* bcnt     = (int*)ws; ws += (NB + 1) * 4;
    int* rowstart = (int*)ws; ws += (size_t)(N_NODES + 4) * 4;
    int* csr_src  = (int*)ws; ws += (size_t)E2 * 4;

    const int* edge_src = eidx;
    const int* edge_dst = eidx + E_EDGES;

    // ---- CSR build: memset + 2 kernels ----
    hipMemsetAsync(bcnt, 0, (NB + 1) * sizeof(int), stream);
    count_scatter_prep<<<NTIL + PREPB, 1024, 0, stream>>>(
        edge_src, edge_dst, Wl, Wr, att, Wt, atth, bcnt, pairbuf);
    bucketize2<<<NB, 1024, 0, stream>>>(pairbuf, bcnt, rowstart, csr_src);

    // ---- two GATv2 layers (fp16 intermediate h16 between them) ----
    const int gemm_gx = (N_NODES + 127) / 128;   // 782: 32 rows/wave, 4 waves/blk
    for (int l = 0; l < 2; ++l) {
        gemm_mfma5<<<gemm_gx, 256, 0, stream>>>(
            (l == 0) ? nullptr : h16, (l == 0) ? x : nullptr,
            Wt + (size_t)l * 32768, xl, xr, N_NODES);
        gat_node10<<<N_NODES / 4, 256, 0, stream>>>(
            xl, xr,
            (l == 0) ? x : nullptr, (l == 0) ? nullptr : h16,
            rowstart, csr_src,
            atth + l * 128, bias + l * 128, gamma + l * 128, beta + l * 128,
            (l == 1) ? out : nullptr, (l == 0) ? h16 : nullptr);
    }
}